// Round 1
// baseline (1272.414 us; speedup 1.0000x reference)
//
#include <hip/hip_runtime.h>
#include <hip/hip_bf16.h>
#include <math.h>
#include <stdint.h>

// Problem constants
constexpr int N_ROWS = 32768;
constexpr int K_DIM  = 4096;
constexpr int R_DIM  = 256;
constexpr int KP     = 3 * R_DIM;   // 768: split-K' for [hi|hi|lo] x [hi|lo|hi]

typedef __bf16 bf16x8 __attribute__((ext_vector_type(8)));
typedef float  f32x4  __attribute__((ext_vector_type(4)));
typedef unsigned short u16x8 __attribute__((ext_vector_type(8)));
typedef unsigned short u16x4 __attribute__((ext_vector_type(4)));

// ---- bf16 helpers (round-to-nearest-even; inputs are finite normals) ----
__device__ __forceinline__ unsigned short f2bf(float x) {
    unsigned u = __float_as_uint(x);
    u += 0x7fffu + ((u >> 16) & 1u);
    return (unsigned short)(u >> 16);
}
__device__ __forceinline__ float bf2f(unsigned short h) {
    return __uint_as_float((unsigned)h << 16);
}

// ---- async global->LDS, 16B per lane, LDS dest = wave-uniform base + lane*16
__device__ __forceinline__ void gl2lds16(const void* gptr, void* lptr) {
    __builtin_amdgcn_global_load_lds(
        (const __attribute__((address_space(1))) unsigned int*)gptr,
        (__attribute__((address_space(3))) unsigned int*)lptr,
        16, 0, 0);
}

// ===========================================================================
// MFMA NT GEMM: C[m,n] = sum_k A[m,k]*B[n,k], A/B bf16 k-major, C fp32.
// 128x128 tile, BK=32, 256 threads = 4 waves (2x2 of 64x64), 16x16x32 MFMA.
// Used for K2: logits M = A' . B'^T with K'=768 (3-term split bf16).
// ===========================================================================
__global__ __launch_bounds__(256)
void gemm_mfma_nt(const unsigned short* __restrict__ A,
                  const unsigned short* __restrict__ B,
                  float* __restrict__ C, int M, int N, int Kc)
{
    __shared__ __align__(16) unsigned short As[128 * 32];
    __shared__ __align__(16) unsigned short Bs[128 * 32];

    const int tid  = threadIdx.x;
    const int wave = tid >> 6, lane = tid & 63;
    const int wm = wave >> 1, wn = wave & 1;
    const long m0 = (long)blockIdx.x * 128;
    const long n0 = (long)blockIdx.y * 128;

    f32x4 acc[4][4] = {};

    const int srow  = lane >> 2;        // 0..15 within 16-row chunk
    const int skoff = (lane & 3) * 8;   // bf16 elem offset within 32-wide row
    const int c0 = wave, c1 = wave + 4; // each wave stages 2 chunks per tile
    const int kq = (lane >> 4) * 8;     // frag k-offset 0,8,16,24
    const int mr = lane & 15;

    for (int k0 = 0; k0 < Kc; k0 += 32) {
        gl2lds16(A + (m0 + c0 * 16 + srow) * (long)Kc + k0 + skoff, &As[c0 * 512]);
        gl2lds16(A + (m0 + c1 * 16 + srow) * (long)Kc + k0 + skoff, &As[c1 * 512]);
        gl2lds16(B + (n0 + c0 * 16 + srow) * (long)Kc + k0 + skoff, &Bs[c0 * 512]);
        gl2lds16(B + (n0 + c1 * 16 + srow) * (long)Kc + k0 + skoff, &Bs[c1 * 512]);
        __syncthreads();

        bf16x8 af[4], bfr[4];
#pragma unroll
        for (int t = 0; t < 4; ++t) {
            af[t]  = *(const bf16x8*)&As[(wm * 64 + t * 16 + mr) * 32 + kq];
            bfr[t] = *(const bf16x8*)&Bs[(wn * 64 + t * 16 + mr) * 32 + kq];
        }
#pragma unroll
        for (int i = 0; i < 4; ++i)
#pragma unroll
            for (int j = 0; j < 4; ++j)
                acc[i][j] = __builtin_amdgcn_mfma_f32_16x16x32_bf16(
                    af[i], bfr[j], acc[i][j], 0, 0, 0);
        __syncthreads();
    }

    // C/D layout: col = lane&15, row = (lane>>4)*4 + reg
    const int col = lane & 15, rquad = (lane >> 4) * 4;
#pragma unroll
    for (int i = 0; i < 4; ++i) {
        const long mrow = m0 + wm * 64 + i * 16 + rquad;
#pragma unroll
        for (int j = 0; j < 4; ++j) {
            float* p = C + mrow * (long)N + n0 + wn * 64 + j * 16 + col;
#pragma unroll
            for (int r = 0; r < 4; ++r) p[(long)r * N] = acc[i][j][r];
        }
    }
}

// ===========================================================================
// Fused softmax + PV:  A = softmax(M, axis=1) written to Mio in place,
//                      C = A @ L  (bf16 MFMA with unnormalized e, scaled by 1/s)
// Grid: N_ROWS/64 blocks of 512 threads (8 waves).
// Pass 1: online (max, sum) per row — one streaming read of M.
// Pass 2: k-tiles of 64 — re-read M, e=exp(x-m), write A=e/s, MFMA e @ LT.
// LT is R_DIM x K_DIM bf16 k-major (pre-transposed L), L2-resident (2 MB).
// ===========================================================================
__global__ __launch_bounds__(512)
void softmax_av(float* __restrict__ Mio,
                const unsigned short* __restrict__ LT,
                float* __restrict__ C)
{
    __shared__ __align__(16) unsigned short Bs[R_DIM * 64]; // 32 KiB (swizzled)
    __shared__ __align__(16) unsigned short As[64 * 64];    //  8 KiB (swizzled)
    __shared__ float sm_m[64], sm_inv[64];

    const int tid  = threadIdx.x;
    const int wave = tid >> 6, lane = tid & 63;
    const long m0 = (long)blockIdx.x * 64;

    // ---------------- Pass 1: online (max, sum) — wave handles 8 rows ------
    for (int rr = 0; rr < 8; ++rr) {
        const int row = wave * 8 + rr;
        const float* rp = Mio + (m0 + row) * (long)K_DIM;
        float m = -3.4e38f, s = 0.f;
#pragma unroll
        for (int it = 0; it < 16; ++it) {
            float4 v = ((const float4*)rp)[lane + 64 * it];
            float cm = fmaxf(fmaxf(v.x, v.y), fmaxf(v.z, v.w));
            if (cm > m) { s *= __expf(m - cm); m = cm; }
            s += __expf(v.x - m) + __expf(v.y - m) +
                 __expf(v.z - m) + __expf(v.w - m);
        }
        // butterfly combine (m, s) across the 64 lanes
#pragma unroll
        for (int off = 1; off < 64; off <<= 1) {
            float om = __shfl_xor(m, off), os = __shfl_xor(s, off);
            float nm = fmaxf(m, om);
            s = s * __expf(m - nm) + os * __expf(om - nm);
            m = nm;
        }
        if (lane == 0) { sm_m[row] = m; sm_inv[row] = 1.f / s; }
    }
    __syncthreads();

    // ---------------- Pass 2: k-loop, exp + A write + MFMA ------------------
    f32x4 acc[2][4] = {};
    const int wm = wave >> 2, wn = wave & 3;  // wave tile: 32 rows x 64 cols
    const int mr = lane & 15;
    const int kq16 = (lane >> 4) * 16;        // byte offset of frag within 32-k

    for (int k0 = 0; k0 < K_DIM; k0 += 64) {
        // ---- stage LT tile (256 r x 64 k) via async DMA, source pre-swizzled
#pragma unroll
        for (int q = 0; q < 4; ++q) {
            const int rbase = q * 64 + wave * 8;
            const int rloc  = rbase + (lane >> 3);
            const int phys  = (lane & 7) * 16;                 // byte in row
            const int kbyte = phys ^ ((rloc & 7) << 4);        // src byte
            gl2lds16((const char*)LT + (long)rloc * (K_DIM * 2) + (long)k0 * 2 + kbyte,
                     &Bs[rbase * 64]);
        }
        // ---- stage A tile (64 rows x 64 k): exp, global A write, LDS bf16 --
#pragma unroll
        for (int p = 0; p < 2; ++p) {
            const int row = p * 32 + wave * 4 + (lane >> 4);
            const int col = (lane & 15) * 4;
            float* gp = Mio + (m0 + row) * (long)K_DIM + k0 + col;
            float4 v = *(const float4*)gp;
            const float mrow = sm_m[row], inv = sm_inv[row];
            float e0 = __expf(v.x - mrow), e1 = __expf(v.y - mrow);
            float e2 = __expf(v.z - mrow), e3 = __expf(v.w - mrow);
            *(float4*)gp = make_float4(e0 * inv, e1 * inv, e2 * inv, e3 * inv);
            u16x4 u;
            u[0] = f2bf(e0); u[1] = f2bf(e1); u[2] = f2bf(e2); u[3] = f2bf(e3);
            const int byte = (row * 128 + col * 2) ^ ((row & 7) << 4);
            *(u16x4*)((char*)As + byte) = u;
        }
        __syncthreads();

        // ---- MFMA: 2x4 tiles x 2 k-slices ----------------------------------
#pragma unroll
        for (int ks = 0; ks < 2; ++ks) {
            bf16x8 af[2], bfr[4];
#pragma unroll
            for (int t = 0; t < 2; ++t) {
                const int arow = wm * 32 + t * 16 + mr;
                const int ab = (arow * 128 + ks * 64 + kq16) ^ ((arow & 7) << 4);
                af[t] = *(const bf16x8*)((const char*)As + ab);
            }
#pragma unroll
            for (int t = 0; t < 4; ++t) {
                const int brow = wn * 64 + t * 16 + mr;
                const int bb = (brow * 128 + ks * 64 + kq16) ^ ((brow & 7) << 4);
                bfr[t] = *(const bf16x8*)((const char*)Bs + bb);
            }
#pragma unroll
            for (int i = 0; i < 2; ++i)
#pragma unroll
                for (int j = 0; j < 4; ++j)
                    acc[i][j] = __builtin_amdgcn_mfma_f32_16x16x32_bf16(
                        af[i], bfr[j], acc[i][j], 0, 0, 0);
        }
        __syncthreads();
    }

    // ---- epilogue: scale by 1/s, write C -----------------------------------
    const int col = lane & 15, rquad = (lane >> 4) * 4;
#pragma unroll
    for (int i = 0; i < 2; ++i) {
        const int lrow0 = wm * 32 + i * 16 + rquad;
#pragma unroll
        for (int j = 0; j < 4; ++j) {
            float* p = C + (m0 + lrow0) * (long)R_DIM + wn * 64 + j * 16 + col;
#pragma unroll
            for (int r = 0; r < 4; ++r)
                p[(long)r * R_DIM] = acc[i][j][r] * sm_inv[lrow0 + r];
        }
    }
}

// ===========================================================================
// Prep kernels
// ===========================================================================
// B' = [L_hi | L_lo | L_hi]  (K_DIM x 768)
__global__ __launch_bounds__(256)
void prep_B(const float* __restrict__ L, unsigned short* __restrict__ Bp)
{
    const long i = (long)blockIdx.x * 256 + threadIdx.x;   // over K_DIM*R_DIM
    const long k = i >> 8; const int r = (int)(i & 255);
    const float x = L[i];
    const unsigned short hi = f2bf(x);
    const unsigned short lo = f2bf(x - bf2f(hi));
    unsigned short* row = Bp + k * KP;
    row[r] = hi; row[R_DIM + r] = lo; row[2 * R_DIM + r] = hi;
}

// LT[r][k] = bf16(L[k][r])  (256 x 4096) — coalesced writes
__global__ __launch_bounds__(256)
void prep_LT(const float* __restrict__ L, unsigned short* __restrict__ LT)
{
    const long i = (long)blockIdx.x * 256 + threadIdx.x;   // over R_DIM*K_DIM
    const long r = i >> 12; const long k = i & 4095;
    LT[r * K_DIM + k] = f2bf(L[k * R_DIM + r]);
}

// ===========================================================================
// fp32 VALU GEMM — fallback path only.
// ===========================================================================
template<bool BT>
__global__ __launch_bounds__(256)
void gemm128(const float* __restrict__ A, const float* __restrict__ B,
             float* __restrict__ C, int M, int N, int Kc)
{
    __shared__ __align__(16) float Asl[16][132];
    __shared__ __align__(16) float Bsl[16][132];

    const int tid = threadIdx.x;
    const int tx = tid & 15, ty = tid >> 4;
    const long m0 = (long)blockIdx.x * 128;
    const long n0 = (long)blockIdx.y * 128;

    float acc[8][8];
#pragma unroll
    for (int i = 0; i < 8; ++i)
#pragma unroll
        for (int j = 0; j < 8; ++j) acc[i][j] = 0.f;

    for (int k0 = 0; k0 < Kc; k0 += 16) {
#pragma unroll
        for (int q = 0; q < 2; ++q) {
            int fi = tid + 256 * q, row = fi >> 2, col = (fi & 3) * 4;
            float4 v = *(const float4*)(A + (m0 + row) * (long)Kc + k0 + col);
            Asl[col + 0][row] = v.x; Asl[col + 1][row] = v.y;
            Asl[col + 2][row] = v.z; Asl[col + 3][row] = v.w;
        }
        if (BT) {
#pragma unroll
            for (int q = 0; q < 2; ++q) {
                int fi = tid + 256 * q, row = fi >> 2, col = (fi & 3) * 4;
                float4 v = *(const float4*)(B + (n0 + row) * (long)Kc + k0 + col);
                Bsl[col + 0][row] = v.x; Bsl[col + 1][row] = v.y;
                Bsl[col + 2][row] = v.z; Bsl[col + 3][row] = v.w;
            }
        } else {
#pragma unroll
            for (int q = 0; q < 2; ++q) {
                int fi = tid + 256 * q, row = fi >> 5, col = (fi & 31) * 4;
                float4 v = *(const float4*)(B + (k0 + row) * (long)N + n0 + col);
                *(float4*)&Bsl[row][col] = v;
            }
        }
        __syncthreads();
#pragma unroll
        for (int kk = 0; kk < 16; ++kk) {
            float a[8], b[8];
            *(float4*)&a[0] = *(const float4*)&Asl[kk][ty * 8];
            *(float4*)&a[4] = *(const float4*)&Asl[kk][ty * 8 + 4];
            *(float4*)&b[0] = *(const float4*)&Bsl[kk][tx * 8];
            *(float4*)&b[4] = *(const float4*)&Bsl[kk][tx * 8 + 4];
#pragma unroll
            for (int i = 0; i < 8; ++i)
#pragma unroll
                for (int j = 0; j < 8; ++j)
                    acc[i][j] = fmaf(a[i], b[j], acc[i][j]);
        }
        __syncthreads();
    }
#pragma unroll
    for (int i = 0; i < 8; ++i) {
        float* p = C + (m0 + ty * 8 + i) * (long)N + n0 + tx * 8;
        *(float4*)p       = make_float4(acc[i][0], acc[i][1], acc[i][2], acc[i][3]);
        *(float4*)(p + 4) = make_float4(acc[i][4], acc[i][5], acc[i][6], acc[i][7]);
    }
}

// ===========================================================================
// K1 with fused split-write: P = A@B (fp32 VALU), epilogue writes
// Ap = [P_hi | P_hi | P_lo] directly (no P materialization, no prep_A pass).
// ===========================================================================
__global__ __launch_bounds__(256)
void gemm128_hl(const float* __restrict__ A, const float* __restrict__ B,
                unsigned short* __restrict__ Ap, int M, int N, int Kc)
{
    __shared__ __align__(16) float Asl[16][132];
    __shared__ __align__(16) float Bsl[16][132];

    const int tid = threadIdx.x;
    const int tx = tid & 15, ty = tid >> 4;
    const long m0 = (long)blockIdx.x * 128;
    const long n0 = (long)blockIdx.y * 128;

    float acc[8][8];
#pragma unroll
    for (int i = 0; i < 8; ++i)
#pragma unroll
        for (int j = 0; j < 8; ++j) acc[i][j] = 0.f;

    for (int k0 = 0; k0 < Kc; k0 += 16) {
#pragma unroll
        for (int q = 0; q < 2; ++q) {
            int fi = tid + 256 * q, row = fi >> 2, col = (fi & 3) * 4;
            float4 v = *(const float4*)(A + (m0 + row) * (long)Kc + k0 + col);
            Asl[col + 0][row] = v.x; Asl[col + 1][row] = v.y;
            Asl[col + 2][row] = v.z; Asl[col + 3][row] = v.w;
        }
#pragma unroll
        for (int q = 0; q < 2; ++q) {
            int fi = tid + 256 * q, row = fi >> 5, col = (fi & 31) * 4;
            float4 v = *(const float4*)(B + (k0 + row) * (long)N + n0 + col);
            *(float4*)&Bsl[row][col] = v;
        }
        __syncthreads();
#pragma unroll
        for (int kk = 0; kk < 16; ++kk) {
            float a[8], b[8];
            *(float4*)&a[0] = *(const float4*)&Asl[kk][ty * 8];
            *(float4*)&a[4] = *(const float4*)&Asl[kk][ty * 8 + 4];
            *(float4*)&b[0] = *(const float4*)&Bsl[kk][tx * 8];
            *(float4*)&b[4] = *(const float4*)&Bsl[kk][tx * 8 + 4];
#pragma unroll
            for (int i = 0; i < 8; ++i)
#pragma unroll
                for (int j = 0; j < 8; ++j)
                    acc[i][j] = fmaf(a[i], b[j], acc[i][j]);
        }
        __syncthreads();
    }
#pragma unroll
    for (int i = 0; i < 8; ++i) {
        const long row = m0 + ty * 8 + i;
        const int  cb  = (int)n0 + tx * 8;
        u16x8 vh, vl;
#pragma unroll
        for (int j = 0; j < 8; ++j) {
            const float x = acc[i][j];
            const unsigned short hi = f2bf(x);
            vh[j] = hi;
            vl[j] = f2bf(x - bf2f(hi));
        }
        unsigned short* rp = Ap + row * KP;
        *(u16x8*)(rp + cb)             = vh;
        *(u16x8*)(rp + R_DIM + cb)     = vh;
        *(u16x8*)(rp + 2 * R_DIM + cb) = vl;
    }
}

// ---------------------------------------------------------------------------
// In-place row softmax (fallback path only)
// ---------------------------------------------------------------------------
__global__ __launch_bounds__(256)
void softmax_rows(float* __restrict__ Mio)
{
    const long n  = blockIdx.x;
    float* row    = Mio + n * (long)K_DIM;
    const int tid = threadIdx.x;

    float4 v[4];
    float lmax = -3.4e38f;
#pragma unroll
    for (int q = 0; q < 4; ++q) {
        v[q] = ((const float4*)row)[tid + 256 * q];
        lmax = fmaxf(lmax, fmaxf(fmaxf(v[q].x, v[q].y), fmaxf(v[q].z, v[q].w)));
    }
    __shared__ float redmax[4], redsum[4];
#pragma unroll
    for (int off = 32; off > 0; off >>= 1)
        lmax = fmaxf(lmax, __shfl_xor(lmax, off));
    if ((tid & 63) == 0) redmax[tid >> 6] = lmax;
    __syncthreads();
    const float gmax = fmaxf(fmaxf(redmax[0], redmax[1]), fmaxf(redmax[2], redmax[3]));

    float lsum = 0.f;
#pragma unroll
    for (int q = 0; q < 4; ++q) {
        v[q].x = __expf(v[q].x - gmax); v[q].y = __expf(v[q].y - gmax);
        v[q].z = __expf(v[q].z - gmax); v[q].w = __expf(v[q].w - gmax);
        lsum += v[q].x + v[q].y + v[q].z + v[q].w;
    }
#pragma unroll
    for (int off = 32; off > 0; off >>= 1)
        lsum += __shfl_xor(lsum, off);
    if ((tid & 63) == 0) redsum[tid >> 6] = lsum;
    __syncthreads();
    const float inv = 1.f / (redsum[0] + redsum[1] + redsum[2] + redsum[3]);
#pragma unroll
    for (int q = 0; q < 4; ++q) {
        v[q].x *= inv; v[q].y *= inv; v[q].z *= inv; v[q].w *= inv;
        ((float4*)row)[tid + 256 * q] = v[q];
    }
}

// ===========================================================================
extern "C" void kernel_launch(void* const* d_in, const int* in_sizes, int n_in,
                              void* d_out, int out_size, void* d_ws, size_t ws_size,
                              hipStream_t stream)
{
    const float* H  = (const float*)d_in[0];
    const float* L  = (const float*)d_in[1];
    const float* Wi = (const float*)d_in[2];

    float* Cout = (float*)d_out;                           // N x R
    float* Aout = (float*)d_out + (size_t)N_ROWS * R_DIM;  // N x K

    const size_t szAp = (size_t)N_ROWS * KP * 2;   // 48 MiB
    const size_t szBp = (size_t)K_DIM * KP * 2;    //  6 MiB
    const size_t szLT = (size_t)R_DIM * K_DIM * 2; //  2 MiB

    if (ws_size >= szAp + szBp + szLT) {
        unsigned short* Ap = (unsigned short*)d_ws;
        unsigned short* Bp = (unsigned short*)((char*)d_ws + szAp);
        unsigned short* LT = (unsigned short*)((char*)d_ws + szAp + szBp);

        // K1: P = H@W_I (fp32 VALU), split [hi|hi|lo] written directly to Ap
        gemm128_hl<<<dim3(N_ROWS / 128, R_DIM / 128), 256, 0, stream>>>(
            H, Wi, Ap, N_ROWS, R_DIM, R_DIM);
        // Prep split B operand + transposed bf16 L
        prep_B<<<dim3((K_DIM * R_DIM) / 256), 256, 0, stream>>>(L, Bp);
        prep_LT<<<dim3((R_DIM * K_DIM) / 256), 256, 0, stream>>>(L, LT);
        // K2: logits M = A'·B'^T (3-term split bf16 MFMA), K'=768
        gemm_mfma_nt<<<dim3(N_ROWS / 128, K_DIM / 128), 256, 0, stream>>>(
            Ap, Bp, Aout, N_ROWS, K_DIM, KP);
        // K3+K4 fused: softmax (A written in place) + C = A@L
        softmax_av<<<dim3(N_ROWS / 64), 512, 0, stream>>>(Aout, LT, Cout);
    } else {
        // Fallback: round-1 fp32 path
        gemm128<false><<<dim3(N_ROWS / 128, R_DIM / 128), 256, 0, stream>>>(
            H, Wi, Cout, N_ROWS, R_DIM, R_DIM);
        gemm128<true><<<dim3(N_ROWS / 128, K_DIM / 128), 256, 0, stream>>>(
            Cout, L, Aout, N_ROWS, K_DIM, R_DIM);
        softmax_rows<<<dim3(N_ROWS), 256, 0, stream>>>(Aout);
        gemm128<false><<<dim3(N_ROWS / 128, R_DIM / 128), 256, 0, stream>>>(
            Aout, L, Cout, N_ROWS, R_DIM, K_DIM);
    }
}